// Round 2
// baseline (287.290 us; speedup 1.0000x reference)
//
#include <hip/hip_runtime.h>

// Problem constants: B=2, L=2048, E=1024, H=16, D=64
// softmax over QUERY axis (columns of the [L,M] score matrix per head).

typedef _Float16 f16x8 __attribute__((ext_vector_type(8)));
typedef _Float16 f16x4 __attribute__((ext_vector_type(4)));
typedef float f32x4 __attribute__((ext_vector_type(4)));

#define MFMA(a, b, c) __builtin_amdgcn_mfma_f32_16x16x32_f16((a), (b), (c), 0, 0, 0)

// ---------------------------------------------------------------------------
// Kernel 1: fp32 -> f16 convert of x  (4096x1024, exact multiple of 4*256)
// ---------------------------------------------------------------------------
__global__ __launch_bounds__(256) void k_convert_x(const float* __restrict__ x,
                                                   _Float16* __restrict__ xb) {
    int i = (blockIdx.x * 256 + threadIdx.x) * 4;
    float4 f = *(const float4*)(x + i);
    f16x4 o = {(_Float16)f.x, (_Float16)f.y, (_Float16)f.z, (_Float16)f.w};
    *(f16x4*)(xb + i) = o;
}

// ---------------------------------------------------------------------------
// Kernel 2: W (k-major [E][E]) -> W^T f16 ([3*E rows = n][E cols = k])
// so the GEMM B-fragment (lane needs contiguous k) reads 16B runs.
// ---------------------------------------------------------------------------
__global__ __launch_bounds__(256) void k_convert_wt(const float* __restrict__ Wq,
                                                    const float* __restrict__ Wk,
                                                    const float* __restrict__ Wv,
                                                    _Float16* __restrict__ wbt) {
    const int jz = blockIdx.z;
    const float* W = (jz == 0) ? Wq : (jz == 1) ? Wk : Wv;
    __shared__ float tile[64][65];
    const int k0 = blockIdx.y * 64, n0 = blockIdx.x * 64;
    for (int e = threadIdx.x; e < 4096; e += 256) {
        int r = e >> 6, c = e & 63;
        tile[r][c] = W[(k0 + r) * 1024 + n0 + c];
    }
    __syncthreads();
    for (int e = threadIdx.x; e < 4096; e += 256) {
        int r = e >> 6, c = e & 63;  // r: n-offset, c: k-offset
        wbt[((size_t)jz * 1024 + n0 + r) * 1024 + k0 + c] = (_Float16)tile[c][r];
    }
}

// ---------------------------------------------------------------------------
// Kernel 3: fused QKV projection GEMM.
// A = xb [4096 x 1024] f16, B^T = wbt [3072 x 1024] f16, bias fp32.
// Epilogue scatters: Q,K -> [BH][L][64]; V -> transposed [BH][64][L].
// 128x128 block tile, 256 threads = 4 waves (2x2), 16x16x32 f16 MFMA.
// ---------------------------------------------------------------------------
__global__ __launch_bounds__(256) void k_proj_gemm(const _Float16* __restrict__ xb,
                                                   const _Float16* __restrict__ wbt,
                                                   const float* __restrict__ bq,
                                                   const float* __restrict__ bk,
                                                   const float* __restrict__ bv,
                                                   _Float16* __restrict__ Qb,
                                                   _Float16* __restrict__ Kb,
                                                   _Float16* __restrict__ Vt) {
    const int n0 = blockIdx.x * 128;  // 24 blocks -> N=3072
    const int m0 = blockIdx.y * 128;  // 32 blocks -> M=4096
    __shared__ _Float16 As[128][40];  // +8 pad, rows 80B (16B aligned)
    __shared__ _Float16 Bs[128][40];
    const int tid = threadIdx.x;
    const int lane = tid & 63, wv = tid >> 6;
    const int l15 = lane & 15, quad = lane >> 4;
    const int wr = wv >> 1, wc = wv & 1;

    f32x4 acc[4][4] = {};
    for (int k0 = 0; k0 < 1024; k0 += 32) {
        __syncthreads();
        for (int j = 0; j < 2; ++j) {
            int chunk = tid + 256 * j;  // 0..511
            int row = chunk >> 2, c = chunk & 3;
            *(uint4*)&As[row][c * 8] = *(const uint4*)&xb[(size_t)(m0 + row) * 1024 + k0 + c * 8];
            *(uint4*)&Bs[row][c * 8] = *(const uint4*)&wbt[(size_t)(n0 + row) * 1024 + k0 + c * 8];
        }
        __syncthreads();
        f16x8 af[4], bf[4];
        for (int i = 0; i < 4; ++i) {
            af[i] = *(const f16x8*)&As[wr * 64 + i * 16 + l15][quad * 8];
            bf[i] = *(const f16x8*)&Bs[wc * 64 + i * 16 + l15][quad * 8];
        }
        for (int i = 0; i < 4; ++i)
            for (int j = 0; j < 4; ++j)
                acc[i][j] = MFMA(af[i], bf[j], acc[i][j]);
    }

    const int proj = n0 >> 10;  // whole block in one of Q/K/V (1024 % 128 == 0)
    const float* bias = (proj == 0) ? bq : (proj == 1) ? bk : bv;
    for (int j = 0; j < 4; ++j) {
        int n = n0 + wc * 64 + j * 16 + l15;
        int nn = n & 1023;
        float bsv = bias[nn];
        int h = nn >> 6, d = nn & 63;
        for (int i = 0; i < 4; ++i) {
            for (int r = 0; r < 4; ++r) {
                int t = m0 + wr * 64 + i * 16 + quad * 4 + r;  // token index
                int b = t >> 11, l = t & 2047;
                _Float16 val = (_Float16)(acc[i][j][r] + bsv);
                int bh = b * 16 + h;
                if (proj == 0)
                    Qb[((size_t)bh * 2048 + l) * 64 + d] = val;
                else if (proj == 1)
                    Kb[((size_t)bh * 2048 + l) * 64 + d] = val;
                else
                    Vt[((size_t)bh * 64 + d) * 2048 + l] = val;
            }
        }
    }
}

// ---------------------------------------------------------------------------
// Kernel 4: column stats. For each (bh, m): c_m = max_l S[l,m],
// rz_m = 1 / sum_l exp(S[l,m]-c_m).  Block: 64 m-columns, loops over l.
// ---------------------------------------------------------------------------
__global__ __launch_bounds__(256) void k_stats(const _Float16* __restrict__ Qb,
                                               const _Float16* __restrict__ Kb,
                                               float* __restrict__ colmax,
                                               float* __restrict__ colrz) {
    const int m0 = blockIdx.x * 64;  // 32 m-tiles
    const int bh = blockIdx.y;       // 32 heads
    __shared__ _Float16 Ks[64][72];  // [m][d], rows 144B (16B-aligned)
    __shared__ _Float16 Qs[64][72];  // [l][d]
    __shared__ float red[4][64][2];
    const int tid = threadIdx.x;
    const int lane = tid & 63, wv = tid >> 6, l15 = lane & 15, quad = lane >> 4;

    // stage K tile once: 64 rows x 128B = 512 uint4 (2 rounds of 256)
    for (int it = 0; it < 2; ++it) {
        int chunk = tid + 256 * it;
        int row = chunk >> 3, c = chunk & 7;
        *(uint4*)&Ks[row][c * 8] = *(const uint4*)&Kb[((size_t)bh * 2048 + m0 + row) * 64 + c * 8];
    }
    float runmax[4], runsum[4];
    for (int s = 0; s < 4; ++s) { runmax[s] = -__builtin_inff(); runsum[s] = 0.f; }
    __syncthreads();
    // B-fragments (K^T) are loop-invariant: load to regs once.
    f16x8 bf[4][2];
    for (int s = 0; s < 4; ++s)
        for (int kc = 0; kc < 2; ++kc)
            bf[s][kc] = *(const f16x8*)&Ks[s * 16 + l15][kc * 32 + quad * 8];

    for (int l0 = 0; l0 < 2048; l0 += 64) {
        __syncthreads();
        for (int it = 0; it < 2; ++it) {
            int chunk = tid + 256 * it;
            int row = chunk >> 3, c = chunk & 7;
            *(uint4*)&Qs[row][c * 8] = *(const uint4*)&Qb[((size_t)bh * 2048 + l0 + row) * 64 + c * 8];
        }
        __syncthreads();
        f16x8 af0 = *(const f16x8*)&Qs[wv * 16 + l15][quad * 8];
        f16x8 af1 = *(const f16x8*)&Qs[wv * 16 + l15][32 + quad * 8];
        for (int s = 0; s < 4; ++s) {
            f32x4 a = {};
            a = MFMA(af0, bf[s][0], a);
            a = MFMA(af1, bf[s][1], a);
            // D layout: lane holds rows l = quad*4+r, col m = s*16+l15.
            float tmax = fmaxf(fmaxf(a[0], a[1]), fmaxf(a[2], a[3]));
            tmax = fmaxf(tmax, __shfl_xor(tmax, 16, 64));
            tmax = fmaxf(tmax, __shfl_xor(tmax, 32, 64));
            float nm = fmaxf(runmax[s], tmax);
            float ssum = __expf(a[0] - nm) + __expf(a[1] - nm) +
                         __expf(a[2] - nm) + __expf(a[3] - nm);
            ssum += __shfl_xor(ssum, 16, 64);
            ssum += __shfl_xor(ssum, 32, 64);
            runsum[s] = runsum[s] * __expf(runmax[s] - nm) + ssum;
            runmax[s] = nm;
        }
    }
    __syncthreads();
    if (lane < 16)
        for (int s = 0; s < 4; ++s) {
            red[wv][s * 16 + l15][0] = runmax[s];
            red[wv][s * 16 + l15][1] = runsum[s];
        }
    __syncthreads();
    if (tid < 64) {
        float m = red[0][tid][0];
        for (int w = 1; w < 4; ++w) m = fmaxf(m, red[w][tid][0]);
        float z = 0.f;
        for (int w = 0; w < 4; ++w) z += red[w][tid][1] * __expf(red[w][tid][0] - m);
        colmax[bh * 2048 + m0 + tid] = m;
        colrz[bh * 2048 + m0 + tid] = 1.0f / z;
    }
}

// ---------------------------------------------------------------------------
// Kernel 5: output. Block: 64 q-rows for one bh; loop m in chunks of 32.
// O[l,d] += exp(S[l,m]-c_m)*rz_m * V[m,d];  P goes C-layout -> LDS -> A-layout.
// ---------------------------------------------------------------------------
__global__ __launch_bounds__(256) void k_attn(const _Float16* __restrict__ Qb,
                                              const _Float16* __restrict__ Kb,
                                              const _Float16* __restrict__ Vt,
                                              const float* __restrict__ colmax,
                                              const float* __restrict__ colrz,
                                              float* __restrict__ out) {
    const int l0 = blockIdx.x * 64;  // 32 l-tiles
    const int bh = blockIdx.y;       // 32 heads
    const int b = bh >> 4, h = bh & 15;
    __shared__ _Float16 Qs[64][72];      // [l][d]
    __shared__ _Float16 Ks[32][72];      // [m][d]
    __shared__ _Float16 Vs[64][40];      // [d][m] (from Vt)
    __shared__ _Float16 Ps[4][16][40];   // per-wave P scratch [l][m]
    const int tid = threadIdx.x, lane = tid & 63, wv = tid >> 6;
    const int l15 = lane & 15, quad = lane >> 4;

    // stage Q tile: 64 rows x 128B = 512 uint4 (2 rounds)
    for (int it = 0; it < 2; ++it) {
        int chunk = tid + 256 * it;
        int row = chunk >> 3, c = chunk & 7;
        *(uint4*)&Qs[row][c * 8] = *(const uint4*)&Qb[((size_t)bh * 2048 + l0 + row) * 64 + c * 8];
    }
    __syncthreads();
    f16x8 qf0 = *(const f16x8*)&Qs[wv * 16 + l15][quad * 8];
    f16x8 qf1 = *(const f16x8*)&Qs[wv * 16 + l15][32 + quad * 8];

    f32x4 oacc[4] = {};
    for (int m0 = 0; m0 < 2048; m0 += 32) {
        __syncthreads();
        {   // stage K: 32 rows x 128B = 256 uint4
            int row = tid >> 3, c = tid & 7;
            *(uint4*)&Ks[row][c * 8] = *(const uint4*)&Kb[((size_t)bh * 2048 + m0 + row) * 64 + c * 8];
        }
        {   // stage V^T tile: 64 d-rows x 32 m = 256 uint4
            int row = tid >> 2, c = tid & 3;
            *(uint4*)&Vs[row][c * 8] = *(const uint4*)&Vt[((size_t)bh * 64 + row) * 2048 + m0 + c * 8];
        }
        __syncthreads();
        // S = Q K^T : per wave [16 l][32 m]
        f32x4 sacc[2];
        for (int s = 0; s < 2; ++s) {
            f32x4 a = {};
            f16x8 kf0 = *(const f16x8*)&Ks[s * 16 + l15][quad * 8];
            f16x8 kf1 = *(const f16x8*)&Ks[s * 16 + l15][32 + quad * 8];
            a = MFMA(qf0, kf0, a);
            a = MFMA(qf1, kf1, a);
            sacc[s] = a;
        }
        // P = exp(S - c_m) * rz_m, write to LDS in [l][m]
        for (int s = 0; s < 2; ++s) {
            int m = m0 + s * 16 + l15;
            float c = colmax[bh * 2048 + m];
            float rz = colrz[bh * 2048 + m];
            for (int r = 0; r < 4; ++r) {
                float p = __expf(sacc[s][r] - c) * rz;
                Ps[wv][quad * 4 + r][s * 16 + l15] = (_Float16)p;
            }
        }
        __syncthreads();
        // PV: A = P [16 l x 32 m], B = V [32 m x 16 d] x4 d-subtiles
        f16x8 pf = *(const f16x8*)&Ps[wv][l15][quad * 8];
        for (int dt = 0; dt < 4; ++dt) {
            f16x8 vf = *(const f16x8*)&Vs[dt * 16 + l15][quad * 8];
            oacc[dt] = MFMA(pf, vf, oacc[dt]);
        }
    }
    // epilogue: fp32 out [B][L][E]
    for (int dt = 0; dt < 4; ++dt)
        for (int r = 0; r < 4; ++r) {
            int l = l0 + wv * 16 + quad * 4 + r;
            out[((size_t)(b * 2048 + l)) * 1024 + h * 64 + dt * 16 + l15] = oacc[dt][r];
        }
}

// ---------------------------------------------------------------------------
// Workspace layout (bytes):
//  0        xb   : 4096*1024 f16          = 8 MB
//  8 MB     wbt  : 3072*1024 f16          = 6 MB
// 14 MB     Qb   : 32*2048*64 f16         = 8 MB
// 22 MB     Kb   : 32*2048*64 f16         = 8 MB
// 30 MB     Vt   : 32*64*2048 f16         = 8 MB
// 38 MB     colmax: 32*2048 f32           = 256 KB
// 38.25 MB  colrz : 32*2048 f32           = 256 KB
// total ~38.5 MB
// ---------------------------------------------------------------------------
extern "C" void kernel_launch(void* const* d_in, const int* in_sizes, int n_in,
                              void* d_out, int out_size, void* d_ws, size_t ws_size,
                              hipStream_t stream) {
    const float* x  = (const float*)d_in[0];
    const float* Wq = (const float*)d_in[1];
    const float* bq = (const float*)d_in[2];
    const float* Wk = (const float*)d_in[3];
    const float* bk = (const float*)d_in[4];
    const float* Wv = (const float*)d_in[5];
    const float* bv = (const float*)d_in[6];
    float* out = (float*)d_out;

    char* w = (char*)d_ws;
    _Float16* xb  = (_Float16*)(w);
    _Float16* wbt = (_Float16*)(w + (size_t)(8 << 20));
    _Float16* Qb  = (_Float16*)(w + (size_t)(14 << 20));
    _Float16* Kb  = (_Float16*)(w + (size_t)(22 << 20));
    _Float16* Vt  = (_Float16*)(w + (size_t)(30 << 20));
    float* colmax = (float*)(w + (size_t)(38 << 20));
    float* colrz  = (float*)(w + (size_t)(38 << 20) + (256 << 10));

    k_convert_x<<<4096, 256, 0, stream>>>(x, xb);
    k_convert_wt<<<dim3(16, 16, 3), 256, 0, stream>>>(Wq, Wk, Wv, wbt);
    k_proj_gemm<<<dim3(24, 32), 256, 0, stream>>>(xb, wbt, bq, bk, bv, Qb, Kb, Vt);
    k_stats<<<dim3(32, 32), 256, 0, stream>>>(Qb, Kb, colmax, colrz);
    k_attn<<<dim3(32, 32), 256, 0, stream>>>(Qb, Kb, Vt, colmax, colrz, out);
}